// Round 2
// baseline (198.663 us; speedup 1.0000x reference)
//
#include <hip/hip_runtime.h>

#define INV_2PI 0.15915494309189535f

// v_sin_f32 takes REVOLUTIONS: computes sin(2*pi*x) directly, no range
// reduction needed (args ~[0,1]). volatile pins sin order so batches
// stream back-to-back through the trans pipe.
__device__ __forceinline__ float vsin_pinned(float x) {
    float r;
    asm volatile("v_sin_f32 %0, %1" : "=v"(r) : "v"(x));
    return r;
}

// Batched diff_round: N independent sins issue back-to-back, then N fmas
// whose operands are long-ready.
template <int N>
__device__ __forceinline__ void dround_batch(float* c) {
    float s[N];
#pragma unroll
    for (int i = 0; i < N; ++i) s[i] = vsin_pinned(c[i]);
#pragma unroll
    for (int i = 0; i < N; ++i) c[i] = __builtin_fmaf(-INV_2PI, s[i], c[i]);
}

// Tail of filter_mask_of_interest once hdr(mask) is in c[16]: eq-combine
// against (hb,vb), hdr(eq), differentiable_and tree -> m[4] per-pixel mask.
__device__ __forceinline__ void filter_tail(float* c, const float* hb,
                                            const float* vb, float* m) {
#pragma unroll
    for (int i = 0; i < 16; ++i) {
        float om = 1.0f - c[i];
        c[i] = __builtin_fmaf(c[i], hb[i & 3], om * vb[i & 3]);
    }
    dround_batch<16>(c); dround_batch<16>(c); dround_batch<16>(c);
    dround_batch<16>(c);
    float p[8];
#pragma unroll
    for (int j = 0; j < 4; ++j) {
        p[2 * j]     = c[4 * j]     * c[4 * j + 1];
        p[2 * j + 1] = c[4 * j + 2] * c[4 * j + 3];
    }
    dround_batch<8>(p);
#pragma unroll
    for (int j = 0; j < 4; ++j) m[j] = p[2 * j] * p[2 * j + 1];
}

// One area's inputs, register-resident (36 VGPRs). Two instances give a
// 2-deep software pipeline: area t+1's loads fly under area t's ~2.7k
// cycles of sin work.
struct AreaBuf {
    float4 q0, q1, q2, q3;   // mask variant 0 (lane's 4 pixels, stride 64)
    float4 a0, a1, a2, a3;   // mask variant 1
    float  i0, i1, i2, i3;   // image
    float4 idv;              // initial_mask_id
};

__device__ __forceinline__ void load_area(AreaBuf& b,
        const float* __restrict__ img, const float4* __restrict__ mask4,
        const float4* __restrict__ alt4, const float* __restrict__ mask_id,
        int area, int lane) {
    area = __builtin_amdgcn_readfirstlane(area);   // SGPR bases
    const size_t base = (size_t)area * 256;
    const float4* mp = mask4 + base + lane;        // 1KB/instr, coalesced
    b.q0 = mp[0]; b.q1 = mp[64]; b.q2 = mp[128]; b.q3 = mp[192];
    const float4* ap = alt4 + base + lane;
    b.a0 = ap[0]; b.a1 = ap[64]; b.a2 = ap[128]; b.a3 = ap[192];
    const float* ip = img + base + lane;           // 256B/instr
    b.i0 = ip[0]; b.i1 = ip[64]; b.i2 = ip[128]; b.i3 = ip[192];
    b.idv = *(const float4*)(mask_id + (size_t)area * 4);  // uniform
}

__device__ __forceinline__ void compute_store(const AreaBuf& b,
        float* __restrict__ out, float* __restrict__ out_alt,
        int area, int lane) {
    area = __builtin_amdgcn_readfirstlane(area);
    const size_t base = (size_t)area * 256;

    // Merged first hdr stage: id channels (->hb) + variant-0 mask as one
    // 20-wide sin stream.
    float c0[20] = { b.idv.x, b.idv.y, b.idv.z, b.idv.w,
                     b.q0.x, b.q0.y, b.q0.z, b.q0.w,
                     b.q1.x, b.q1.y, b.q1.z, b.q1.w,
                     b.q2.x, b.q2.y, b.q2.z, b.q2.w,
                     b.q3.x, b.q3.y, b.q3.z, b.q3.w };
    dround_batch<20>(c0); dround_batch<20>(c0); dround_batch<20>(c0);

    float hb[4] = { c0[0], c0[1], c0[2], c0[3] };
    float vb[4];
#pragma unroll
    for (int k = 0; k < 4; ++k) vb[k] = 1.0f - hb[k];

    float m0[4];
    filter_tail(c0 + 4, hb, vb, m0);

    float c1[16] = { b.a0.x, b.a0.y, b.a0.z, b.a0.w,
                     b.a1.x, b.a1.y, b.a1.z, b.a1.w,
                     b.a2.x, b.a2.y, b.a2.z, b.a2.w,
                     b.a3.x, b.a3.y, b.a3.z, b.a3.w };
    dround_batch<16>(c1); dround_batch<16>(c1); dround_batch<16>(c1);
    float m1[4];
    filter_tail(c1, hb, vb, m1);

    // Joint 6-stage butterfly carrying all 4 partial sums.
    float im[4] = { b.i0, b.i1, b.i2, b.i3 };
    float sm0 = 0.f, si0 = 0.f, sm1 = 0.f, si1 = 0.f;
#pragma unroll
    for (int j = 0; j < 4; ++j) {
        sm0 += m0[j]; si0 += m0[j] * im[j];
        sm1 += m1[j]; si1 += m1[j] * im[j];
    }
#pragma unroll
    for (int off = 32; off; off >>= 1) {
        sm0 += __shfl_xor(sm0, off, 64);
        si0 += __shfl_xor(si0, off, 64);
        sm1 += __shfl_xor(sm1, off, 64);
        si1 += __shfl_xor(si1, off, 64);
    }

    // Guard 0/0: m >= 0, so sm==0 implies all m==0 -> output 0.
    const float mean0 = (sm0 > 0.f) ? (si0 / sm0) : 0.f;
    const float mean1 = (sm1 > 0.f) ? (si1 / sm1) : 0.f;

    float* d0 = out     + base + lane;
    float* d1 = out_alt + base + lane;
#pragma unroll
    for (int k = 0; k < 4; ++k) {
        d0[64 * k] = m0[k] * mean0;
        d1[64 * k] = m1[k] * mean1;
    }
}

// Persistent-ish waves: each wave owns AREAS_PER_WAVE areas (grid-strided)
// and runs a 2-deep register double-buffer: loads for the NEXT area issue
// (pinned by sched_barrier) before computing the CURRENT one, so exposed
// memory latency is paid once per wave, not once per area.
__global__ __launch_bounds__(256) void De_conv_areas_kernel(
    const float* __restrict__ img,       // [A,256,1] f32
    const float* __restrict__ mask,      // [A,256,4] f32
    const float* __restrict__ mask_alt,  // [A,256,4] f32
    const float* __restrict__ mask_id,   // [A,4]     f32
    float* __restrict__ out,             // [A,256]   f32
    float* __restrict__ out_alt,         // [A,256]   f32
    int n_areas, int n_waves)
{
    const int lane = threadIdx.x & 63;
    const int w = blockIdx.x * (blockDim.x >> 6) + (threadIdx.x >> 6);
    if (w >= n_areas) return;

    const float4* mask4 = (const float4*)mask;
    const float4* alt4  = (const float4*)mask_alt;

    AreaBuf A, B;
    int tA = w;
    int tB = w + n_waves;
    load_area(A, img, mask4, alt4, mask_id, tA, lane);

    for (;;) {
        if (tB < n_areas) load_area(B, img, mask4, alt4, mask_id, tB, lane);
        __builtin_amdgcn_sched_barrier(0);           // don't sink B's loads
        compute_store(A, out, out_alt, tA, lane);
        if (tB >= n_areas) break;

        tA = tB + n_waves;
        if (tA < n_areas) load_area(A, img, mask4, alt4, mask_id, tA, lane);
        __builtin_amdgcn_sched_barrier(0);           // don't sink A's loads
        compute_store(B, out, out_alt, tB, lane);
        if (tA >= n_areas) break;
        tB = tA + n_waves;
    }
}

extern "C" void kernel_launch(void* const* d_in, const int* in_sizes, int n_in,
                              void* d_out, int out_size, void* d_ws, size_t ws_size,
                              hipStream_t stream) {
    // setup_inputs() order (all float32 per reference):
    // 0: resized_image      [B,N,16,16,1]
    // 1: mask_combined      [B,N,16,16,4]
    // 2: mask_combined_alt  [B,N,16,16,4]
    // 3: initial_mask_id    [B,N,4]
    // 4: mask_new_bi_channel (unused)
    // 5: mask_index          (unused)
    const float* img      = (const float*)d_in[0];
    const float* mask     = (const float*)d_in[1];
    const float* mask_alt = (const float*)d_in[2];
    const float* mask_id  = (const float*)d_in[3];

    const int n_areas = out_size / 512;             // B*N = 16384
    float* out     = (float*)d_out;
    float* out_alt = out + (size_t)n_areas * 256;

    // 4 areas per wave -> 4096 waves; 4 waves per 256-thread block.
    const int areas_per_wave = 4;
    const int n_waves = (n_areas + areas_per_wave - 1) / areas_per_wave;
    const int waves_per_block = 4;
    const int blocks = (n_waves + waves_per_block - 1) / waves_per_block;
    De_conv_areas_kernel<<<blocks, 256, 0, stream>>>(
        img, mask, mask_alt, mask_id, out, out_alt, n_areas, n_waves);
}